// Round 2
// baseline (193.472 us; speedup 1.0000x reference)
//
#include <hip/hip_runtime.h>

#define T_DIM 1024
#define D_DIM 64
#define WIN   128
#define TILE  128      // output rows per block (stats/band)
#define KROWS 256      // staged rows = TILE + WIN
#define NTHR  512
#define NBH   32       // B*H
#define ZBLK  1024
#define ZTHR  512

typedef __attribute__((ext_vector_type(8))) short short8;
typedef __attribute__((ext_vector_type(4))) float f32x4;

__device__ __forceinline__ unsigned int pack2bf(float a, float b) {
  unsigned int ua = __float_as_uint(a);
  unsigned int ub = __float_as_uint(b);
  ua = (ua + 0x7fffu + ((ua >> 16) & 1u)) >> 16;   // RNE f32->bf16
  ub = (ub + 0x7fffu + ((ub >> 16) & 1u)) >> 16;
  return ua | (ub << 16);
}

// ---------------------------------------------------------------------------
// Kernel Z: zero all output except uint4s fully inside the band; zero suminv.
// ---------------------------------------------------------------------------
__global__ __launch_bounds__(ZTHR)
void zero_kernel(f32x4* __restrict__ out, float* __restrict__ suminv)
{
  int gid = blockIdx.x * ZTHR + threadIdx.x;
  if (gid < NBH) suminv[gid] = 0.f;
  const int total = NBH * T_DIM * (T_DIM / 4);   // 8388608 uint4
  const f32x4 z = {0.f, 0.f, 0.f, 0.f};
  for (int idx = gid; idx < total; idx += ZBLK * ZTHR) {
    int i_t = (idx >> 8) & (T_DIM - 1);          // row index within T
    int j0  = (idx & 255) << 2;                  // first col of this uint4
    bool in_band = (j0 >= i_t - WIN) && (j0 + 3 <= i_t);  // band_kernel covers it
    if (!in_band) out[idx] = z;
  }
}

// ---------------------------------------------------------------------------
// Shared helpers: stage 256 rows as swizzled bf16, compute norms.
// ---------------------------------------------------------------------------
__device__ __forceinline__ void stage_rows(const float* __restrict__ Ebh, int base,
                                           uint4* Kb4, int tid)
{
  #pragma unroll
  for (int it = 0; it < (KROWS * 8) / NTHR; ++it) {
    int u = tid + it * NTHR;
    int r = u >> 3, c = u & 7;                   // c = 16B unit (8 bf16)
    int gr = base - WIN + r;
    uint4 w = make_uint4(0u, 0u, 0u, 0u);
    if (gr >= 0) {
      const float4 f0 = *(const float4*)(Ebh + gr * D_DIM + c * 8);
      const float4 f1 = *(const float4*)(Ebh + gr * D_DIM + c * 8 + 4);
      w.x = pack2bf(f0.x, f0.y); w.y = pack2bf(f0.z, f0.w);
      w.z = pack2bf(f1.x, f1.y); w.w = pack2bf(f1.z, f1.w);
    }
    Kb4[(r << 3) + (c ^ (r & 7))] = w;
  }
}

__device__ __forceinline__ void compute_norms(const uint4* Kb4, float* ln,
                                              int lane, int wv)
{
  const unsigned short* Kbs = (const unsigned short*)Kb4;
  int u = lane >> 3, e = lane & 7;               // element d = lane
  for (int r = wv; r < KROWS; r += 8) {
    unsigned short bits = Kbs[(((r << 3) + (u ^ (r & 7))) << 3) + e];
    float x = __uint_as_float(((unsigned int)bits) << 16);
    float s = x * x;
    #pragma unroll
    for (int m = 1; m < 64; m <<= 1) s += __shfl_xor(s, m);
    if (lane == 0) ln[r] = sqrtf(s);
  }
}

// ---------------------------------------------------------------------------
// Kernel S: per-(b,h) sum of 1/denom via windowed rowsums (MFMA).
// ---------------------------------------------------------------------------
__global__ __launch_bounds__(NTHR, 1)
void stats_kernel(const float* __restrict__ E, float* __restrict__ suminv)
{
  __shared__ uint4 Kb4[KROWS * 8];               // 32 KB
  __shared__ float ln[KROWS];

  const int tid = threadIdx.x, lane = tid & 63, wv = tid >> 6;
  const int blk = blockIdx.x, bh = blk >> 3, base = (blk & 7) * TILE;
  const float* Ebh = E + (size_t)bh * (T_DIM * D_DIM);

  stage_rows(Ebh, base, Kb4, tid);
  __syncthreads();
  compute_norms(Kb4, ln, lane, wv);
  __syncthreads();

  const short8* KbF = (const short8*)Kb4;
  const int mrow = lane & 15, kg = lane >> 4;
  const int ar = WIN + wv * 16 + mrow;
  short8 a0 = KbF[(ar << 3) + (kg ^ (ar & 7))];
  short8 a1 = KbF[(ar << 3) + ((kg + 4) ^ (ar & 7))];

  float ni[4], sacc[4] = {0.f, 0.f, 0.f, 0.f};
  #pragma unroll
  for (int g = 0; g < 4; ++g) ni[g] = ln[WIN + wv * 16 + kg * 4 + g];

  #pragma unroll
  for (int t = 0; t < 16; ++t) {
    int br = t * 16 + mrow;
    short8 b0 = KbF[(br << 3) + (kg ^ (br & 7))];
    short8 b1 = KbF[(br << 3) + ((kg + 4) ^ (br & 7))];
    f32x4 ca = {0.f, 0.f, 0.f, 0.f};
    ca = __builtin_amdgcn_mfma_f32_16x16x32_bf16(a0, b0, ca, 0, 0, 0);
    ca = __builtin_amdgcn_mfma_f32_16x16x32_bf16(a1, b1, ca, 0, 0, 0);
    int rj = t * 16 + mrow;
    float nj = ln[rj];
    #pragma unroll
    for (int g = 0; g < 4; ++g) {
      int li = wv * 16 + kg * 4 + g;
      float cv = ca[g] / (ni[g] * nj + 1e-8f);
      bool valid = (rj >= li) && (rj <= li + WIN) && (base - WIN + rj >= 0);
      sacc[g] += valid ? cv : 0.f;
    }
  }
  float wsum = 0.f;
  #pragma unroll
  for (int g = 0; g < 4; ++g) {
    float s = sacc[g];
    #pragma unroll
    for (int m = 1; m < 16; m <<= 1) s += __shfl_xor(s, m);
    if (mrow == 0) wsum += 2048.f / (s + 2048.f);   // 1/denom (T=1024: 2T=2048)
  }
  #pragma unroll
  for (int m = 1; m < 64; m <<= 1) wsum += __shfl_xor(wsum, m);
  if (lane == 0) atomicAdd(&suminv[bh], wsum);
}

// ---------------------------------------------------------------------------
// Kernel B: recompute scores, softmax in registers, store band only.
// ---------------------------------------------------------------------------
__global__ __launch_bounds__(NTHR, 1)
void band_kernel(const float* __restrict__ E, const float* __restrict__ suminv,
                 float* __restrict__ out)
{
  __shared__ uint4 Kb4[KROWS * 8];               // 32 KB
  __shared__ float ln[KROWS];

  const int tid = threadIdx.x, lane = tid & 63, wv = tid >> 6;
  const int blk = blockIdx.x, bh = blk >> 3, base = (blk & 7) * TILE;
  const float* Ebh = E + (size_t)bh * (T_DIM * D_DIM);
  const float rsum = 1.0f / suminv[bh];

  stage_rows(Ebh, base, Kb4, tid);
  __syncthreads();
  compute_norms(Kb4, ln, lane, wv);
  __syncthreads();

  const short8* KbF = (const short8*)Kb4;
  const int mrow = lane & 15, kg = lane >> 4;
  const int ar = WIN + wv * 16 + mrow;
  short8 a0 = KbF[(ar << 3) + (kg ^ (ar & 7))];
  short8 a1 = KbF[(ar << 3) + ((kg + 4) ^ (ar & 7))];

  f32x4 acc[16];
  #pragma unroll
  for (int t = 0; t < 16; ++t) {
    int br = t * 16 + mrow;
    short8 b0 = KbF[(br << 3) + (kg ^ (br & 7))];
    short8 b1 = KbF[(br << 3) + ((kg + 4) ^ (br & 7))];
    f32x4 ca = {0.f, 0.f, 0.f, 0.f};
    ca = __builtin_amdgcn_mfma_f32_16x16x32_bf16(a0, b0, ca, 0, 0, 0);
    ca = __builtin_amdgcn_mfma_f32_16x16x32_bf16(a1, b1, ca, 0, 0, 0);
    acc[t] = ca;
  }

  // corr + windowed rowsum (C layout: col = lane&15, row = kg*4+g)
  float ni[4], sacc[4] = {0.f, 0.f, 0.f, 0.f};
  #pragma unroll
  for (int g = 0; g < 4; ++g) ni[g] = ln[WIN + wv * 16 + kg * 4 + g];

  #pragma unroll
  for (int t = 0; t < 16; ++t) {
    int rj = t * 16 + mrow;
    float nj = ln[rj];
    #pragma unroll
    for (int g = 0; g < 4; ++g) {
      int li = wv * 16 + kg * 4 + g;
      float cv = acc[t][g] / (ni[g] * nj + 1e-8f);
      acc[t][g] = cv;
      bool valid = (rj >= li) && (rj <= li + WIN) && (base - WIN + rj >= 0);
      sacc[g] += valid ? cv : 0.f;
    }
  }
  float fit[4], mx[4], esum[4], rinv[4];
  #pragma unroll
  for (int g = 0; g < 4; ++g) {
    float s = sacc[g];
    #pragma unroll
    for (int m = 1; m < 16; m <<= 1) s += __shfl_xor(s, m);  // all 16 lanes get sum
    fit[g] = (2048.f / (s + 2048.f)) * rsum;                 // fitness_i
    mx[g] = -1e30f;
  }

  // masked value then in-register softmax
  #pragma unroll
  for (int t = 0; t < 16; ++t) {
    int rj = t * 16 + mrow;
    #pragma unroll
    for (int g = 0; g < 4; ++g) {
      int li = wv * 16 + kg * 4 + g;
      bool valid = (rj >= li) && (rj <= li + WIN) && (base - WIN + rj >= 0);
      float v = valid ? (acc[t][g] + 1.0f) * 0.5f * fit[g] : -1e30f;
      acc[t][g] = v;
      mx[g] = fmaxf(mx[g], v);
    }
  }
  #pragma unroll
  for (int g = 0; g < 4; ++g) {
    #pragma unroll
    for (int m = 1; m < 16; m <<= 1) mx[g] = fmaxf(mx[g], __shfl_xor(mx[g], m));
    esum[g] = 0.f;
  }
  #pragma unroll
  for (int t = 0; t < 16; ++t) {
    #pragma unroll
    for (int g = 0; g < 4; ++g) {
      float e = __expf(acc[t][g] - mx[g]);   // masked -> 0
      acc[t][g] = e;
      esum[g] += e;
    }
  }
  #pragma unroll
  for (int g = 0; g < 4; ++g) {
    float s = esum[g];
    #pragma unroll
    for (int m = 1; m < 16; m <<= 1) s += __shfl_xor(s, m);
    rinv[g] = 1.0f / s;
  }

  // band stores straight from registers (64B-aligned 64B segments per 16 lanes)
  float* outbh = out + (size_t)bh * T_DIM * T_DIM;
  #pragma unroll
  for (int t = 0; t < 16; ++t) {
    int rj = t * 16 + mrow;
    int j = base - WIN + rj;
    #pragma unroll
    for (int g = 0; g < 4; ++g) {
      int li = wv * 16 + kg * 4 + g;
      bool valid = (rj >= li) && (rj <= li + WIN) && (j >= 0);
      if (valid) outbh[(size_t)(base + li) * T_DIM + j] = acc[t][g] * rinv[g];
    }
  }
}

extern "C" void kernel_launch(void* const* d_in, const int* in_sizes, int n_in,
                              void* d_out, int out_size, void* d_ws, size_t ws_size,
                              hipStream_t stream) {
  const float* E = (const float*)d_in[0];
  float* out = (float*)d_out;
  float* suminv = (float*)d_ws;                  // 32 floats used
  hipLaunchKernelGGL(zero_kernel, dim3(ZBLK), dim3(ZTHR), 0, stream,
                     (f32x4*)out, suminv);
  hipLaunchKernelGGL(stats_kernel, dim3(256), dim3(NTHR), 0, stream, E, suminv);
  hipLaunchKernelGGL(band_kernel, dim3(256), dim3(NTHR), 0, stream, E, suminv, out);
}

// Round 4
// 176.133 us; speedup vs baseline: 1.0984x; 1.0984x over previous
//
#include <hip/hip_runtime.h>

#define T_DIM 1024
#define D_DIM 64
#define WIN   128
#define TILE  64       // output rows per block (stats/band)
#define KROWS 192      // staged rows = TILE + WIN
#define NT    12       // KROWS/16 col-tiles
#define NTHR  256      // 4 waves
#define NBLK  512      // 32 (b,h) * 16 tiles
#define NBH   32
#define FBLK  2048
#define FTHR  256

typedef __attribute__((ext_vector_type(8))) short short8;
typedef __attribute__((ext_vector_type(4))) float f32x4;

__device__ __forceinline__ unsigned int pack2bf(float a, float b) {
  unsigned int ua = __float_as_uint(a);
  unsigned int ub = __float_as_uint(b);
  ua = (ua + 0x7fffu + ((ua >> 16) & 1u)) >> 16;   // RNE f32->bf16
  ub = (ub + 0x7fffu + ((ub >> 16) & 1u)) >> 16;
  return ua | (ub << 16);
}

// ---------------------------------------------------------------------------
// Fill: unconditional zero of the whole output (band overwritten later).
// ---------------------------------------------------------------------------
__global__ __launch_bounds__(FTHR)
void fill_kernel(f32x4* __restrict__ out)
{
  const f32x4 z = {0.f, 0.f, 0.f, 0.f};
  const int total = NBH * T_DIM * (T_DIM / 4);   // 8388608
  for (int idx = blockIdx.x * FTHR + threadIdx.x; idx < total; idx += FBLK * FTHR)
    __builtin_nontemporal_store(z, &out[idx]);
}

// ---------------------------------------------------------------------------
// Stage KROWS rows as swizzled bf16 + norms from f32 source (3 shfls).
// ---------------------------------------------------------------------------
__device__ __forceinline__ void stage_and_norms(const float* __restrict__ Ebh,
                                                int base, uint4* Kb4, float* ln,
                                                int tid)
{
  #pragma unroll
  for (int it = 0; it < (KROWS * 8) / NTHR; ++it) {   // 6 iters
    int u = tid + it * NTHR;
    int r = u >> 3, c = u & 7;                        // c = 16B unit (8 bf16)
    int gr = base - WIN + r;
    uint4 w = make_uint4(0u, 0u, 0u, 0u);
    float ss = 0.f;
    if (gr >= 0) {
      const float4 f0 = *(const float4*)(Ebh + gr * D_DIM + c * 8);
      const float4 f1 = *(const float4*)(Ebh + gr * D_DIM + c * 8 + 4);
      w.x = pack2bf(f0.x, f0.y); w.y = pack2bf(f0.z, f0.w);
      w.z = pack2bf(f1.x, f1.y); w.w = pack2bf(f1.z, f1.w);
      ss = f0.x*f0.x + f0.y*f0.y + f0.z*f0.z + f0.w*f0.w
         + f1.x*f1.x + f1.y*f1.y + f1.z*f1.z + f1.w*f1.w;
    }
    Kb4[(r << 3) + (c ^ (r & 7))] = w;
    ss += __shfl_xor(ss, 1);
    ss += __shfl_xor(ss, 2);
    ss += __shfl_xor(ss, 4);
    if (c == 0) ln[r] = sqrtf(ss);
  }
}

// ---------------------------------------------------------------------------
// Stats: per-block partial of sum(1/denom); plain store (no init needed).
// ---------------------------------------------------------------------------
__global__ __launch_bounds__(NTHR, 2)
void stats_kernel(const float* __restrict__ E, float* __restrict__ partials)
{
  __shared__ uint4 Kb4[KROWS * 8];        // 24 KB
  __shared__ float ln[KROWS];
  __shared__ float wpart[4];

  const int tid = threadIdx.x, lane = tid & 63, wv = tid >> 6;
  const int blk = blockIdx.x, bh = blk >> 4, base = (blk & 15) * TILE;
  const float* Ebh = E + (size_t)bh * (T_DIM * D_DIM);

  stage_and_norms(Ebh, base, Kb4, ln, tid);
  __syncthreads();

  const short8* KbF = (const short8*)Kb4;
  const int mrow = lane & 15, kg = lane >> 4;
  const int ar = WIN + wv * 16 + mrow;
  short8 a0 = KbF[(ar << 3) + (kg ^ (ar & 7))];
  short8 a1 = KbF[(ar << 3) + ((kg + 4) ^ (ar & 7))];

  float ni[4], sacc[4] = {0.f, 0.f, 0.f, 0.f};
  #pragma unroll
  for (int g = 0; g < 4; ++g) ni[g] = ln[WIN + wv * 16 + kg * 4 + g];

  #pragma unroll
  for (int t = 0; t < NT; ++t) {
    if (t < wv || t > wv + 8) continue;   // provably no valid (i,j) outside
    int br = t * 16 + mrow;
    short8 b0 = KbF[(br << 3) + (kg ^ (br & 7))];
    short8 b1 = KbF[(br << 3) + ((kg + 4) ^ (br & 7))];
    f32x4 ca = {0.f, 0.f, 0.f, 0.f};
    ca = __builtin_amdgcn_mfma_f32_16x16x32_bf16(a0, b0, ca, 0, 0, 0);
    ca = __builtin_amdgcn_mfma_f32_16x16x32_bf16(a1, b1, ca, 0, 0, 0);
    int rj = t * 16 + mrow;
    float nj = ln[rj];
    #pragma unroll
    for (int g = 0; g < 4; ++g) {
      int li = wv * 16 + kg * 4 + g;
      float cv = ca[g] / (ni[g] * nj + 1e-8f);
      bool valid = (rj >= li) && (rj <= li + WIN) && (base - WIN + rj >= 0);
      sacc[g] += valid ? cv : 0.f;
    }
  }
  float wsum = 0.f;
  #pragma unroll
  for (int g = 0; g < 4; ++g) {
    float s = sacc[g];
    #pragma unroll
    for (int m = 1; m < 16; m <<= 1) s += __shfl_xor(s, m);
    if (mrow == 0) wsum += 2048.f / (s + 2048.f);     // 1/denom  (2T = 2048)
  }
  #pragma unroll
  for (int m = 1; m < 64; m <<= 1) wsum += __shfl_xor(wsum, m);
  if (lane == 0) wpart[wv] = wsum;
  __syncthreads();
  if (tid == 0) partials[blk] = wpart[0] + wpart[1] + wpart[2] + wpart[3];
}

// ---------------------------------------------------------------------------
// Band: recompute scores, softmax in registers, store band values only.
// ---------------------------------------------------------------------------
__global__ __launch_bounds__(NTHR, 2)
void band_kernel(const float* __restrict__ E, const float* __restrict__ partials,
                 float* __restrict__ out)
{
  __shared__ uint4 Kb4[KROWS * 8];        // 24 KB
  __shared__ float ln[KROWS];
  __shared__ float s_rsum;

  const int tid = threadIdx.x, lane = tid & 63, wv = tid >> 6;
  const int blk = blockIdx.x, bh = blk >> 4, base = (blk & 15) * TILE;
  const float* Ebh = E + (size_t)bh * (T_DIM * D_DIM);

  // suminv for this (b,h): 16 partial slots
  if (tid < 16) {
    float v = partials[(bh << 4) + tid];
    #pragma unroll
    for (int m = 1; m < 16; m <<= 1) v += __shfl_xor(v, m);
    if (tid == 0) s_rsum = 1.0f / v;
  }

  stage_and_norms(Ebh, base, Kb4, ln, tid);
  __syncthreads();

  const float rsum = s_rsum;
  const short8* KbF = (const short8*)Kb4;
  const int mrow = lane & 15, kg = lane >> 4;
  const int ar = WIN + wv * 16 + mrow;
  short8 a0 = KbF[(ar << 3) + (kg ^ (ar & 7))];
  short8 a1 = KbF[(ar << 3) + ((kg + 4) ^ (ar & 7))];

  f32x4 acc[NT];
  float ni[4], sacc[4] = {0.f, 0.f, 0.f, 0.f};
  #pragma unroll
  for (int g = 0; g < 4; ++g) ni[g] = ln[WIN + wv * 16 + kg * 4 + g];

  #pragma unroll
  for (int t = 0; t < NT; ++t) {
    if (t < wv || t > wv + 8) continue;
    int br = t * 16 + mrow;
    short8 b0 = KbF[(br << 3) + (kg ^ (br & 7))];
    short8 b1 = KbF[(br << 3) + ((kg + 4) ^ (br & 7))];
    f32x4 ca = {0.f, 0.f, 0.f, 0.f};
    ca = __builtin_amdgcn_mfma_f32_16x16x32_bf16(a0, b0, ca, 0, 0, 0);
    ca = __builtin_amdgcn_mfma_f32_16x16x32_bf16(a1, b1, ca, 0, 0, 0);
    int rj = t * 16 + mrow;
    float nj = ln[rj];
    #pragma unroll
    for (int g = 0; g < 4; ++g) {
      int li = wv * 16 + kg * 4 + g;
      float cv = ca[g] / (ni[g] * nj + 1e-8f);
      ca[g] = cv;
      bool valid = (rj >= li) && (rj <= li + WIN) && (base - WIN + rj >= 0);
      sacc[g] += valid ? cv : 0.f;
    }
    acc[t] = ca;
  }

  float fit[4], mx[4], esum[4], rinv[4];
  #pragma unroll
  for (int g = 0; g < 4; ++g) {
    float s = sacc[g];
    #pragma unroll
    for (int m = 1; m < 16; m <<= 1) s += __shfl_xor(s, m);
    fit[g] = (2048.f / (s + 2048.f)) * rsum;          // fitness_i
    mx[g] = -1e30f;
    esum[g] = 0.f;
  }

  #pragma unroll
  for (int t = 0; t < NT; ++t) {
    if (t < wv || t > wv + 8) continue;
    int rj = t * 16 + mrow;
    #pragma unroll
    for (int g = 0; g < 4; ++g) {
      int li = wv * 16 + kg * 4 + g;
      bool valid = (rj >= li) && (rj <= li + WIN) && (base - WIN + rj >= 0);
      float v = valid ? (acc[t][g] + 1.0f) * 0.5f * fit[g] : -1e30f;
      acc[t][g] = v;
      mx[g] = fmaxf(mx[g], v);
    }
  }
  #pragma unroll
  for (int g = 0; g < 4; ++g) {
    #pragma unroll
    for (int m = 1; m < 16; m <<= 1) mx[g] = fmaxf(mx[g], __shfl_xor(mx[g], m));
  }
  #pragma unroll
  for (int t = 0; t < NT; ++t) {
    if (t < wv || t > wv + 8) continue;
    #pragma unroll
    for (int g = 0; g < 4; ++g) {
      float e = __expf(acc[t][g] - mx[g]);            // masked -> 0
      acc[t][g] = e;
      esum[g] += e;
    }
  }
  #pragma unroll
  for (int g = 0; g < 4; ++g) {
    float s = esum[g];
    #pragma unroll
    for (int m = 1; m < 16; m <<= 1) s += __shfl_xor(s, m);
    rinv[g] = 1.0f / s;
  }

  // band stores straight from registers (4x 64B segments per store instr)
  float* outbh = out + (size_t)bh * T_DIM * T_DIM;
  #pragma unroll
  for (int t = 0; t < NT; ++t) {
    if (t < wv || t > wv + 8) continue;
    int rj = t * 16 + mrow;
    int j = base - WIN + rj;
    #pragma unroll
    for (int g = 0; g < 4; ++g) {
      int li = wv * 16 + kg * 4 + g;
      bool valid = (rj >= li) && (rj <= li + WIN) && (j >= 0);
      if (valid) outbh[(size_t)(base + li) * T_DIM + j] = acc[t][g] * rinv[g];
    }
  }
}

extern "C" void kernel_launch(void* const* d_in, const int* in_sizes, int n_in,
                              void* d_out, int out_size, void* d_ws, size_t ws_size,
                              hipStream_t stream) {
  const float* E = (const float*)d_in[0];
  float* out = (float*)d_out;
  float* partials = (float*)d_ws;                  // 512 floats used
  hipLaunchKernelGGL(fill_kernel, dim3(FBLK), dim3(FTHR), 0, stream, (f32x4*)out);
  hipLaunchKernelGGL(stats_kernel, dim3(NBLK), dim3(NTHR), 0, stream, E, partials);
  hipLaunchKernelGGL(band_kernel, dim3(NBLK), dim3(NTHR), 0, stream, E, partials, out);
}

// Round 6
// 165.605 us; speedup vs baseline: 1.1683x; 1.0636x over previous
//
#include <hip/hip_runtime.h>

#define T_DIM 1024
#define D_DIM 64
#define WIN   128
#define TILE  64       // output rows per block (stats/band)
#define KROWS 192      // staged rows = TILE + WIN
#define NT    12       // KROWS/16 col-tiles
#define NTHR  256      // 4 waves
#define NBLK  512      // 32 (b,h) * 16 tiles
#define NBH   32

typedef __attribute__((ext_vector_type(8))) short short8;
typedef __attribute__((ext_vector_type(4))) float f32x4;

__device__ __forceinline__ unsigned int pack2bf(float a, float b) {
  unsigned int ua = __float_as_uint(a);
  unsigned int ub = __float_as_uint(b);
  ua = (ua + 0x7fffu + ((ua >> 16) & 1u)) >> 16;   // RNE f32->bf16
  ub = (ub + 0x7fffu + ((ub >> 16) & 1u)) >> 16;
  return ua | (ub << 16);
}

// ---------------------------------------------------------------------------
// Stage KROWS rows as swizzled bf16 + norms from f32 source (3 shfls).
// ---------------------------------------------------------------------------
__device__ __forceinline__ void stage_and_norms(const float* __restrict__ Ebh,
                                                int base, uint4* Kb4, float* ln,
                                                int tid)
{
  #pragma unroll
  for (int it = 0; it < (KROWS * 8) / NTHR; ++it) {   // 6 iters
    int u = tid + it * NTHR;
    int r = u >> 3, c = u & 7;                        // c = 16B unit (8 bf16)
    int gr = base - WIN + r;
    uint4 w = make_uint4(0u, 0u, 0u, 0u);
    float ss = 0.f;
    if (gr >= 0) {
      const float4 f0 = *(const float4*)(Ebh + gr * D_DIM + c * 8);
      const float4 f1 = *(const float4*)(Ebh + gr * D_DIM + c * 8 + 4);
      w.x = pack2bf(f0.x, f0.y); w.y = pack2bf(f0.z, f0.w);
      w.z = pack2bf(f1.x, f1.y); w.w = pack2bf(f1.z, f1.w);
      ss = f0.x*f0.x + f0.y*f0.y + f0.z*f0.z + f0.w*f0.w
         + f1.x*f1.x + f1.y*f1.y + f1.z*f1.z + f1.w*f1.w;
    }
    Kb4[(r << 3) + (c ^ (r & 7))] = w;
    ss += __shfl_xor(ss, 1);
    ss += __shfl_xor(ss, 2);
    ss += __shfl_xor(ss, 4);
    if (c == 0) ln[r] = sqrtf(ss);
  }
}

// ---------------------------------------------------------------------------
// Stats: per-block partial of sum(1/denom); plain store (no init needed).
// ---------------------------------------------------------------------------
__global__ __launch_bounds__(NTHR, 2)
void stats_kernel(const float* __restrict__ E, float* __restrict__ partials)
{
  __shared__ uint4 Kb4[KROWS * 8];        // 24 KB
  __shared__ float ln[KROWS];
  __shared__ float wpart[4];

  const int tid = threadIdx.x, lane = tid & 63, wv = tid >> 6;
  const int blk = blockIdx.x, bh = blk >> 4, base = (blk & 15) * TILE;
  const float* Ebh = E + (size_t)bh * (T_DIM * D_DIM);

  stage_and_norms(Ebh, base, Kb4, ln, tid);
  __syncthreads();

  const short8* KbF = (const short8*)Kb4;
  const int mrow = lane & 15, kg = lane >> 4;
  const int ar = WIN + wv * 16 + mrow;
  short8 a0 = KbF[(ar << 3) + (kg ^ (ar & 7))];
  short8 a1 = KbF[(ar << 3) + ((kg + 4) ^ (ar & 7))];

  float ni[4], sacc[4] = {0.f, 0.f, 0.f, 0.f};
  #pragma unroll
  for (int g = 0; g < 4; ++g) ni[g] = ln[WIN + wv * 16 + kg * 4 + g];

  #pragma unroll
  for (int t = 0; t < NT; ++t) {
    if (t < wv || t > wv + 8) continue;   // provably no valid (i,j) outside
    int br = t * 16 + mrow;
    short8 b0 = KbF[(br << 3) + (kg ^ (br & 7))];
    short8 b1 = KbF[(br << 3) + ((kg + 4) ^ (br & 7))];
    f32x4 ca = {0.f, 0.f, 0.f, 0.f};
    ca = __builtin_amdgcn_mfma_f32_16x16x32_bf16(a0, b0, ca, 0, 0, 0);
    ca = __builtin_amdgcn_mfma_f32_16x16x32_bf16(a1, b1, ca, 0, 0, 0);
    int rj = t * 16 + mrow;
    float nj = ln[rj];
    #pragma unroll
    for (int g = 0; g < 4; ++g) {
      int li = wv * 16 + kg * 4 + g;
      float cv = ca[g] / (ni[g] * nj + 1e-8f);
      bool valid = (rj >= li) && (rj <= li + WIN) && (base - WIN + rj >= 0);
      sacc[g] += valid ? cv : 0.f;
    }
  }
  float wsum = 0.f;
  #pragma unroll
  for (int g = 0; g < 4; ++g) {
    float s = sacc[g];
    #pragma unroll
    for (int m = 1; m < 16; m <<= 1) s += __shfl_xor(s, m);
    if (mrow == 0) wsum += 2048.f / (s + 2048.f);     // 1/denom  (2T = 2048)
  }
  #pragma unroll
  for (int m = 1; m < 64; m <<= 1) wsum += __shfl_xor(wsum, m);
  if (lane == 0) wpart[wv] = wsum;
  __syncthreads();
  if (tid == 0) partials[blk] = wpart[0] + wpart[1] + wpart[2] + wpart[3];
}

// ---------------------------------------------------------------------------
// Band: recompute scores, softmax in registers, write COMPLETE rows:
// zero uint4s outside [q0,q1] (disjoint from band cover), band scalars inside.
// ---------------------------------------------------------------------------
__global__ __launch_bounds__(NTHR, 2)
void band_kernel(const float* __restrict__ E, const float* __restrict__ partials,
                 float* __restrict__ out)
{
  __shared__ uint4 Kb4[KROWS * 8];        // 24 KB
  __shared__ float ln[KROWS];
  __shared__ float s_rsum;

  const int tid = threadIdx.x, lane = tid & 63, wv = tid >> 6;
  const int blk = blockIdx.x, bh = blk >> 4, base = (blk & 15) * TILE;
  const float* Ebh = E + (size_t)bh * (T_DIM * D_DIM);

  // suminv for this (b,h): 16 partial slots
  if (tid < 16) {
    float v = partials[(bh << 4) + tid];
    #pragma unroll
    for (int m = 1; m < 16; m <<= 1) v += __shfl_xor(v, m);
    if (tid == 0) s_rsum = 1.0f / v;
  }

  stage_and_norms(Ebh, base, Kb4, ln, tid);
  __syncthreads();

  // ---- zero pass: thread tid owns uint4-column q=tid for all TILE rows ----
  // Issued after the barrier so the stores drain underneath MFMA/softmax.
  {
    const f32x4 z = {0.f, 0.f, 0.f, 0.f};
    f32x4* outq = (f32x4*)out + ((size_t)bh * T_DIM + base) * (T_DIM / 4);
    const int q = tid;
    #pragma unroll 4
    for (int r = 0; r < TILE; ++r) {
      int i = base + r;
      int q0 = (i >= WIN) ? ((i - WIN) >> 2) : 0;
      int q1 = i >> 2;
      if (q < q0 || q > q1)
        __builtin_nontemporal_store(z, &outq[r * (T_DIM / 4) + q]);
    }
  }

  const float rsum = s_rsum;
  const short8* KbF = (const short8*)Kb4;
  const int mrow = lane & 15, kg = lane >> 4;
  const int ar = WIN + wv * 16 + mrow;
  short8 a0 = KbF[(ar << 3) + (kg ^ (ar & 7))];
  short8 a1 = KbF[(ar << 3) + ((kg + 4) ^ (ar & 7))];

  f32x4 acc[NT];
  float ni[4], sacc[4] = {0.f, 0.f, 0.f, 0.f};
  #pragma unroll
  for (int g = 0; g < 4; ++g) ni[g] = ln[WIN + wv * 16 + kg * 4 + g];

  #pragma unroll
  for (int t = 0; t < NT; ++t) {
    if (t < wv || t > wv + 8) continue;
    int br = t * 16 + mrow;
    short8 b0 = KbF[(br << 3) + (kg ^ (br & 7))];
    short8 b1 = KbF[(br << 3) + ((kg + 4) ^ (br & 7))];
    f32x4 ca = {0.f, 0.f, 0.f, 0.f};
    ca = __builtin_amdgcn_mfma_f32_16x16x32_bf16(a0, b0, ca, 0, 0, 0);
    ca = __builtin_amdgcn_mfma_f32_16x16x32_bf16(a1, b1, ca, 0, 0, 0);
    int rj = t * 16 + mrow;
    float nj = ln[rj];
    #pragma unroll
    for (int g = 0; g < 4; ++g) {
      int li = wv * 16 + kg * 4 + g;
      float cv = ca[g] / (ni[g] * nj + 1e-8f);
      ca[g] = cv;
      bool valid = (rj >= li) && (rj <= li + WIN) && (base - WIN + rj >= 0);
      sacc[g] += valid ? cv : 0.f;
    }
    acc[t] = ca;
  }

  float fit[4], mx[4], esum[4], rinv[4];
  #pragma unroll
  for (int g = 0; g < 4; ++g) {
    float s = sacc[g];
    #pragma unroll
    for (int m = 1; m < 16; m <<= 1) s += __shfl_xor(s, m);
    fit[g] = (2048.f / (s + 2048.f)) * rsum;          // fitness_i
    mx[g] = -1e30f;
    esum[g] = 0.f;
  }

  #pragma unroll
  for (int t = 0; t < NT; ++t) {
    if (t < wv || t > wv + 8) continue;
    int rj = t * 16 + mrow;
    #pragma unroll
    for (int g = 0; g < 4; ++g) {
      int li = wv * 16 + kg * 4 + g;
      bool valid = (rj >= li) && (rj <= li + WIN) && (base - WIN + rj >= 0);
      float v = valid ? (acc[t][g] + 1.0f) * 0.5f * fit[g] : -1e30f;
      acc[t][g] = v;
      mx[g] = fmaxf(mx[g], v);
    }
  }
  #pragma unroll
  for (int g = 0; g < 4; ++g) {
    #pragma unroll
    for (int m = 1; m < 16; m <<= 1) mx[g] = fmaxf(mx[g], __shfl_xor(mx[g], m));
  }
  #pragma unroll
  for (int t = 0; t < NT; ++t) {
    if (t < wv || t > wv + 8) continue;
    #pragma unroll
    for (int g = 0; g < 4; ++g) {
      float e = __expf(acc[t][g] - mx[g]);            // masked -> 0
      acc[t][g] = e;
      esum[g] += e;
    }
  }
  #pragma unroll
  for (int g = 0; g < 4; ++g) {
    float s = esum[g];
    #pragma unroll
    for (int m = 1; m < 16; m <<= 1) s += __shfl_xor(s, m);
    rinv[g] = 1.0f / s;
  }

  // band cover stores: all j in [4*q0, 4*q1+3]; masked entries store 0
  // (exp(-1e30-mx)=0), so cover + zero pass tile each row exactly.
  float* outbh = out + (size_t)bh * T_DIM * T_DIM;
  #pragma unroll
  for (int t = 0; t < NT; ++t) {
    if (t < wv || t > wv + 8) continue;
    int rj = t * 16 + mrow;
    int j = base - WIN + rj;
    #pragma unroll
    for (int g = 0; g < 4; ++g) {
      int li = wv * 16 + kg * 4 + g;
      int i = base + li;
      int jlo = (i >= WIN) ? ((i - WIN) & ~3) : 0;
      int jhi = (i & ~3) + 3;
      if (j >= jlo && j <= jhi)
        __builtin_nontemporal_store(acc[t][g] * rinv[g],
                                    &outbh[(size_t)i * T_DIM + j]);
    }
  }
}

extern "C" void kernel_launch(void* const* d_in, const int* in_sizes, int n_in,
                              void* d_out, int out_size, void* d_ws, size_t ws_size,
                              hipStream_t stream) {
  const float* E = (const float*)d_in[0];
  float* out = (float*)d_out;
  float* partials = (float*)d_ws;                  // 512 floats used
  hipLaunchKernelGGL(stats_kernel, dim3(NBLK), dim3(NTHR), 0, stream, E, partials);
  hipLaunchKernelGGL(band_kernel, dim3(NBLK), dim3(NTHR), 0, stream, E, partials, out);
}